// Round 17
// baseline (2978.465 us; speedup 1.0000x reference)
//
#include <hip/hip_runtime.h>

typedef __attribute__((ext_vector_type(8))) short short8;
typedef __attribute__((ext_vector_type(4))) float f32x4;
typedef __attribute__((ext_vector_type(4))) unsigned short u16x4;
typedef __attribute__((ext_vector_type(4))) unsigned int u32x4;

#define S_ 512
#define B_ 64
#define E_ 256
#define H_ 256
#define NSTEP 1023  // 2*S - 1 sequential cell steps per chain

// ---------- helpers ----------
__device__ __forceinline__ unsigned short f2bf(float f) {
  unsigned u = __builtin_bit_cast(unsigned, f);
  return (unsigned short)((u + 0x7fffu + ((u >> 16) & 1u)) >> 16);  // RNE
}
__device__ __forceinline__ float bf2f(unsigned short h) {
  unsigned u = ((unsigned)h) << 16;
  return __builtin_bit_cast(float, u);
}
__device__ __forceinline__ float sigm(float x) { return 1.f / (1.f + __expf(-x)); }
__device__ __forceinline__ float tanh_(float x) {
  x = fminf(fmaxf(x, -15.f), 15.f);
  float e = __expf(-2.f * x);
  return (1.f - e) / (1.f + e);
}

// ---------- prep: x -> bf16; wx/wh packed rows p=jc*4+gate, NATURAL columns; bias combined ----------
__global__ __launch_bounds__(256) void prep9(
    const float* __restrict__ x,
    const float* __restrict__ wih_f, const float* __restrict__ whh_f,
    const float* __restrict__ bih_f, const float* __restrict__ bhh_f,
    const float* __restrict__ wih_b, const float* __restrict__ whh_b,
    const float* __restrict__ bih_b, const float* __restrict__ bhh_b,
    short* __restrict__ x_bf, short* __restrict__ wx, short* __restrict__ wh,
    float* __restrict__ bias_p)
{
  long i0 = (long)blockIdx.x * blockDim.x + threadIdx.x;
  long stride = (long)gridDim.x * blockDim.x;
  const long NX = (long)S_ * B_ * E_;
  const long NW = 2L * 1024 * 256;
  const long NB = 2L * 1024;

  for (long i = i0; i < NX; i += stride) x_bf[i] = (short)f2bf(x[i]);

  for (long i = i0; i < NW; i += stride) {
    int ch  = (int)(i >> 18);
    int rem = (int)(i & 262143);
    int p   = rem >> 8;              // packed row 0..1023
    int k   = rem & 255;
    int jc  = p >> 2, g = p & 3;
    long j  = (long)(g * 256 + jc);  // original gate row
    wx[i] = (short)f2bf((ch ? wih_b : wih_f)[j * 256 + k]);
    wh[i] = (short)f2bf((ch ? whh_b : whh_f)[j * 256 + k]);
  }

  for (long i = i0; i < NB; i += stride) {
    int ch = (int)(i >> 10);
    int p  = (int)(i & 1023);
    int jc = p >> 2, g = p & 3;
    int j  = g * 256 + jc;
    bias_p[i] = ch ? (bih_b[j] + bhh_b[j]) : (bih_f[j] + bhh_f[j]);
  }
}

// ---------- xz precompute (bias folded), bf16; layout xz[ch][t][jc 256][b 64][g 4] ----------
__global__ __launch_bounds__(512, 2) void xz_gemm9(
    const short* __restrict__ x_bf, const short* __restrict__ wx,
    const float* __restrict__ bias_p, short* __restrict__ xz)
{
  const int bid = blockIdx.x;
  const int ch = bid >> 9, t = bid & 511;
  const int tid = threadIdx.x;
  const int wave = tid >> 6, lane = tid & 63;
  const int l15 = lane & 15, l4 = lane >> 4;

  const short* W = wx + (long)ch * 1024 * 256;
  const short* X = x_bf + (long)t * B_ * E_;

  f32x4 acc[8][4];
#pragma unroll
  for (int mt = 0; mt < 8; ++mt)
#pragma unroll
    for (int nt = 0; nt < 4; ++nt) acc[mt][nt] = (f32x4){0.f, 0.f, 0.f, 0.f};

#pragma unroll
  for (int ks = 0; ks < 8; ++ks) {
    int k0 = ks * 32 + l4 * 8;
    short8 bfr[4];
#pragma unroll
    for (int nt = 0; nt < 4; ++nt)
      bfr[nt] = *(const short8*)(X + (long)(nt * 16 + l15) * E_ + k0);
#pragma unroll
    for (int mt = 0; mt < 8; ++mt) {
      int p = (wave * 8 + mt) * 16 + l15;
      short8 af = *(const short8*)(W + (long)p * 256 + k0);
#pragma unroll
      for (int nt = 0; nt < 4; ++nt)
        acc[mt][nt] = __builtin_amdgcn_mfma_f32_16x16x32_bf16(af, bfr[nt], acc[mt][nt], 0, 0, 0);
    }
  }

#pragma unroll
  for (int mt = 0; mt < 8; ++mt) {
    int jc = (wave * 8 + mt) * 4 + l4;
    f32x4 b4 = *(const f32x4*)(bias_p + ch * 1024 + jc * 4);
#pragma unroll
    for (int nt = 0; nt < 4; ++nt) {
      int b = nt * 16 + l15;
      u16x4 v;
#pragma unroll
      for (int g = 0; g < 4; ++g) v[g] = f2bf(acc[mt][nt][g] + b4[g]);
      long off = (((long)(ch * 512 + t) * 256 + jc) * 64 + b) * 4;
      *(u16x4*)(xz + off) = v;
    }
  }
}

// ---------- v17 LSTM: v10 poison-ring + single-asm double-probe spin (syntax fixed) ----------
// Identical to v10 except the spin: two probe sets of 4 dword loads pipelined inside ONE
// asm block (no compiler boundary -> no async register clobber). vmcnt(4) resolves the
// older set (and drains this thread's poison/xz stores, preserving the induction);
// both exits vmcnt(0) BEFORE copying the accepted set. gfx950 syntax: offset: BEFORE sc1.
__global__ __launch_bounds__(512) void lstm17(
    const short* __restrict__ wh, const short* __restrict__ xz,
    short* __restrict__ hring, float* __restrict__ out)
{
  const int bid  = blockIdx.x;
  const int ch   = bid >> 4;
  const int bs   = (bid >> 2) & 3;
  const int role = bid & 3;
  const int tid  = threadIdx.x;
  const int wave = tid >> 6, lane = tid & 63;
  const int l15 = lane & 15, l4 = lane >> 4;

  __shared__ short hin[16 * 256];   // 8 KB: staged h_{t-1}, XOR-swizzled
  __shared__ short hout[16 * 64];   // 2 KB: this block's new h cols, XOR-swizzled

  const short* whc = wh + (long)ch * 1024 * 256;

  // register-resident weight tiles: rows role*256 + wave*32 + mt*16 + l15
  short8 ah[2][8];
#pragma unroll
  for (int mt = 0; mt < 2; ++mt)
#pragma unroll
    for (int ks = 0; ks < 8; ++ks)
      ah[mt][ks] = *(const short8*)(whc + (long)(role * 256 + wave * 32 + mt * 16 + l15) * 256 + ks * 32 + l4 * 8);

  float cst[2], hmax[2];
#pragma unroll
  for (int mt = 0; mt < 2; ++mt) { cst[mt] = 0.f; hmax[mt] = -2.f; }

  short* rb = hring + ch * 16384;        // ch base (shorts)
  const int swzr = (l15 & 7) << 4;

  // per-thread store/poison coords (tid<256): 16 rows x 16 chunks of 8B
  const int sb = tid >> 4, sc = tid & 15;
  // per-thread spin/stage coords: 16 rows x 32 chunks of 16B
  const int pb = tid >> 5, pc = tid & 31;

  for (int t = 0; t < NSTEP; ++t) {
    int tok;
    if (ch == 0) tok = (t + 1) >> 1;
    else         tok = (t == NSTEP - 1) ? (S_ - 1) : ((t & 1) ? (t >> 1) : (t >> 1) + 1);

    // xz addends (normal cached loads; constant data)
    u16x4 xq[2];
#pragma unroll
    for (int mt = 0; mt < 2; ++mt) {
      int jc = role * 64 + wave * 8 + mt * 4 + l4;
      long off = (((long)(ch * 512 + tok) * 256 + jc) * 64 + (bs * 16 + l15)) * 4;
      xq[mt] = *(const u16x4*)(xz + off);
    }

    // ---- poison own rectangle in slot (t+1)&3 (drained by the spin's vmcnt(4)) ----
    if (tid < 256) {
      short* pa = rb + ((t + 1) & 3) * 32768 + (bs * 16 + sb) * 256 + role * 64 + sc * 4;
      unsigned long long pv = 0xFFFFFFFFFFFFFFFFull;
      asm volatile("global_store_dwordx2 %0, %1, off sc1" :: "v"(pa), "v"(pv) : "memory");
    }

    // ---- double-probe spin (single asm block): data IS the flag ----
    {
      const short* ga = rb + ((t + 3) & 3) * 32768 + (bs * 16 + pb) * 256 + pc * 8;
      unsigned d0, d1, d2, d3, t0, t1, t2, t3, m;
      asm volatile(
        "global_load_dword %0, %9, off sc1\n\t"
        "global_load_dword %1, %9, off offset:4 sc1\n\t"
        "global_load_dword %2, %9, off offset:8 sc1\n\t"
        "global_load_dword %3, %9, off offset:12 sc1\n\t"
        "global_load_dword %4, %9, off sc1\n\t"
        "global_load_dword %5, %9, off offset:4 sc1\n\t"
        "global_load_dword %6, %9, off offset:8 sc1\n\t"
        "global_load_dword %7, %9, off offset:12 sc1\n\t"
        "Lsp%=:\n\t"
        "s_waitcnt vmcnt(4)\n\t"              // set0 resolved (+ drains poison/xz)
        "v_max_u32 %8, %0, %1\n\t"
        "v_max_u32 %8, %8, %2\n\t"
        "v_max_u32 %8, %8, %3\n\t"
        "v_cmp_eq_u32 vcc, -1, %8\n\t"        // lane bad iff any dword == 0xFFFFFFFF
        "s_cbranch_vccz Ld0%=\n\t"            // no lane bad -> accept set0
        "global_load_dword %0, %9, off sc1\n\t"
        "global_load_dword %1, %9, off offset:4 sc1\n\t"
        "global_load_dword %2, %9, off offset:8 sc1\n\t"
        "global_load_dword %3, %9, off offset:12 sc1\n\t"
        "s_waitcnt vmcnt(4)\n\t"              // set1 resolved
        "v_max_u32 %8, %4, %5\n\t"
        "v_max_u32 %8, %8, %6\n\t"
        "v_max_u32 %8, %8, %7\n\t"
        "v_cmp_eq_u32 vcc, -1, %8\n\t"
        "s_cbranch_vccz Ld1%=\n\t"            // accept set1
        "global_load_dword %4, %9, off sc1\n\t"
        "global_load_dword %5, %9, off offset:4 sc1\n\t"
        "global_load_dword %6, %9, off offset:8 sc1\n\t"
        "global_load_dword %7, %9, off offset:12 sc1\n\t"
        "s_branch Lsp%=\n\t"
        "Ld1%=:\n\t"
        "s_waitcnt vmcnt(0)\n\t"              // drain in-flight set0 BEFORE copying
        "v_mov_b32 %0, %4\n\t"
        "v_mov_b32 %1, %5\n\t"
        "v_mov_b32 %2, %6\n\t"
        "v_mov_b32 %3, %7\n\t"
        "s_branch Lend%=\n\t"
        "Ld0%=:\n\t"
        "s_waitcnt vmcnt(0)\n\t"              // drain in-flight set1 (writes t*, dead)
        "Lend%=:"
        : "+v"(d0), "+v"(d1), "+v"(d2), "+v"(d3),
          "+v"(t0), "+v"(t1), "+v"(t2), "+v"(t3), "=&v"(m)
        : "v"(ga)
        : "vcc", "memory");
      u32x4 hv = {d0, d1, d2, d3};
      *(u32x4*)((char*)hin + pb * 512 + ((pc * 16) ^ ((pb & 7) << 4))) = hv;
    }
    __syncthreads();

    // ---- recurrent MFMAs: 2 M-tiles x 8 k-steps ----
    f32x4 acc[2];
    acc[0] = (f32x4){0.f, 0.f, 0.f, 0.f};
    acc[1] = (f32x4){0.f, 0.f, 0.f, 0.f};
    const char* hr = (const char*)hin + l15 * 512;
#pragma unroll
    for (int ks = 0; ks < 8; ++ks) {
      short8 hfr = *(const short8*)(hr + ((ks * 64 + l4 * 16) ^ swzr));
      acc[0] = __builtin_amdgcn_mfma_f32_16x16x32_bf16(ah[0][ks], hfr, acc[0], 0, 0, 0);
      acc[1] = __builtin_amdgcn_mfma_f32_16x16x32_bf16(ah[1][ks], hfr, acc[1], 0, 0, 0);
    }

    // ---- gates / state; stash new h cols in hout (LDS, swizzled) ----
#pragma unroll
    for (int mt = 0; mt < 2; ++mt) {
      float zi = acc[mt][0] + bf2f(xq[mt][0]);
      float zf = acc[mt][1] + bf2f(xq[mt][1]);
      float zg = acc[mt][2] + bf2f(xq[mt][2]);
      float zo = acc[mt][3] + bf2f(xq[mt][3]);
      float cc = cst[mt];
      cc = sigm(zf) * cc + sigm(zi) * tanh_(zg);
      float hh = sigm(zo) * tanh_(cc);
      cst[mt] = cc;
      hmax[mt] = fmaxf(hmax[mt], hh);
      int lc = wave * 8 + mt * 4 + l4;  // local col 0..63
      *(short*)((char*)hout + l15 * 128 + ((lc * 2) ^ ((l15 & 7) << 4))) = (short)f2bf(hh);
    }
    __syncthreads();

    // ---- data store to slot t&3: block-synchronized burst (full-sector coalescing),
    //      NO drain, NO flag (visibility rides the next spin) ----
    if (tid < 256) {
      unsigned long long val =
          *(const unsigned long long*)((const char*)hout + sb * 128 + ((sc * 8) ^ ((sb & 7) << 4)));
      short* ga2 = rb + (t & 3) * 32768 + (bs * 16 + sb) * 256 + role * 64 + sc * 4;
      asm volatile("global_store_dwordx2 %0, %1, off sc1" :: "v"(ga2), "v"(val) : "memory");
    }
    // no trailing barrier: hout reuse is ordered by the next iteration's mid barrier,
    // hin reuse by the collective post-gates barrier above.
  }

  // ---- final: running maxes ----
#pragma unroll
  for (int mt = 0; mt < 2; ++mt) {
    int jc = role * 64 + wave * 8 + mt * 4 + l4;
    out[(long)(bs * 16 + l15) * (2 * H_) + ch * H_ + jc] = hmax[mt];
  }
}

extern "C" void kernel_launch(void* const* d_in, const int* in_sizes, int n_in,
                              void* d_out, int out_size, void* d_ws, size_t ws_size,
                              hipStream_t stream) {
  const float* x     = (const float*)d_in[0];
  const float* wih_f = (const float*)d_in[1];
  const float* whh_f = (const float*)d_in[2];
  const float* bih_f = (const float*)d_in[3];
  const float* bhh_f = (const float*)d_in[4];
  const float* wih_b = (const float*)d_in[5];
  const float* whh_b = (const float*)d_in[6];
  const float* bih_b = (const float*)d_in[7];
  const float* bhh_b = (const float*)d_in[8];

  char* ws = (char*)d_ws;
  short* x_bf   = (short*)(ws);                 // 16,777,216 B (dead after xz_gemm9)
  short* hring  = (short*)(ws);                 // 262,144 B ring (reuses x_bf region)
  short* wx     = (short*)(ws + 16777216);      //  1,048,576 B
  short* wh     = (short*)(ws + 17825792);      //  1,048,576 B
  float* bias_p = (float*)(ws + 18874368);      //      8,192 B
  short* xz     = (short*)(ws + 18882560);      // 134,217,728 B (bf16)

  const size_t NEED = 18882560UL + 134217728UL;   // 153,100,288
  if (ws_size < NEED) return;

  prep9<<<2048, 256, 0, stream>>>(x, wih_f, whh_f, bih_f, bhh_f,
                                  wih_b, whh_b, bih_b, bhh_b,
                                  x_bf, wx, wh, bias_p);
  xz_gemm9<<<1024, 512, 0, stream>>>(x_bf, wx, bias_p, xz);

  // x_bf dead; init ring: slots 0..2 = poison (0xFF bytes), slot 3 = zeros (h_{-1} = 0).
  hipMemsetAsync(ws, 0xFF, 196608, stream);
  hipMemsetAsync(ws + 196608, 0, 65536, stream);

  lstm17<<<32, 512, 0, stream>>>(wh, xz, hring, (float*)d_out);
}

// Round 18
// 2079.710 us; speedup vs baseline: 1.4322x; 1.4322x over previous
//
#include <hip/hip_runtime.h>

typedef __attribute__((ext_vector_type(8))) short short8;
typedef __attribute__((ext_vector_type(4))) float f32x4;
typedef __attribute__((ext_vector_type(4))) unsigned short u16x4;
typedef __attribute__((ext_vector_type(4))) unsigned int u32x4;

#define S_ 512
#define B_ 64
#define E_ 256
#define H_ 256
#define NSTEP 1023  // 2*S - 1 sequential cell steps per chain

// ---------- helpers ----------
__device__ __forceinline__ unsigned short f2bf(float f) {
  unsigned u = __builtin_bit_cast(unsigned, f);
  return (unsigned short)((u + 0x7fffu + ((u >> 16) & 1u)) >> 16);  // RNE
}
__device__ __forceinline__ float bf2f(unsigned short h) {
  unsigned u = ((unsigned)h) << 16;
  return __builtin_bit_cast(float, u);
}
__device__ __forceinline__ float sigm(float x) { return 1.f / (1.f + __expf(-x)); }
__device__ __forceinline__ float tanh_(float x) {
  x = fminf(fmaxf(x, -15.f), 15.f);
  float e = __expf(-2.f * x);
  return (1.f - e) / (1.f + e);
}

// ---------- prep: x -> bf16; wx/wh packed rows p=jc*4+gate, NATURAL columns; bias combined ----------
__global__ __launch_bounds__(256) void prep9(
    const float* __restrict__ x,
    const float* __restrict__ wih_f, const float* __restrict__ whh_f,
    const float* __restrict__ bih_f, const float* __restrict__ bhh_f,
    const float* __restrict__ wih_b, const float* __restrict__ whh_b,
    const float* __restrict__ bih_b, const float* __restrict__ bhh_b,
    short* __restrict__ x_bf, short* __restrict__ wx, short* __restrict__ wh,
    float* __restrict__ bias_p)
{
  long i0 = (long)blockIdx.x * blockDim.x + threadIdx.x;
  long stride = (long)gridDim.x * blockDim.x;
  const long NX = (long)S_ * B_ * E_;
  const long NW = 2L * 1024 * 256;
  const long NB = 2L * 1024;

  for (long i = i0; i < NX; i += stride) x_bf[i] = (short)f2bf(x[i]);

  for (long i = i0; i < NW; i += stride) {
    int ch  = (int)(i >> 18);
    int rem = (int)(i & 262143);
    int p   = rem >> 8;              // packed row 0..1023
    int k   = rem & 255;
    int jc  = p >> 2, g = p & 3;
    long j  = (long)(g * 256 + jc);  // original gate row
    wx[i] = (short)f2bf((ch ? wih_b : wih_f)[j * 256 + k]);
    wh[i] = (short)f2bf((ch ? whh_b : whh_f)[j * 256 + k]);
  }

  for (long i = i0; i < NB; i += stride) {
    int ch = (int)(i >> 10);
    int p  = (int)(i & 1023);
    int jc = p >> 2, g = p & 3;
    int j  = g * 256 + jc;
    bias_p[i] = ch ? (bih_b[j] + bhh_b[j]) : (bih_f[j] + bhh_f[j]);
  }
}

// ---------- xz precompute (bias folded), bf16; layout xz[ch][t][jc 256][b 64][g 4] ----------
__global__ __launch_bounds__(512, 2) void xz_gemm9(
    const short* __restrict__ x_bf, const short* __restrict__ wx,
    const float* __restrict__ bias_p, short* __restrict__ xz)
{
  const int bid = blockIdx.x;
  const int ch = bid >> 9, t = bid & 511;
  const int tid = threadIdx.x;
  const int wave = tid >> 6, lane = tid & 63;
  const int l15 = lane & 15, l4 = lane >> 4;

  const short* W = wx + (long)ch * 1024 * 256;
  const short* X = x_bf + (long)t * B_ * E_;

  f32x4 acc[8][4];
#pragma unroll
  for (int mt = 0; mt < 8; ++mt)
#pragma unroll
    for (int nt = 0; nt < 4; ++nt) acc[mt][nt] = (f32x4){0.f, 0.f, 0.f, 0.f};

#pragma unroll
  for (int ks = 0; ks < 8; ++ks) {
    int k0 = ks * 32 + l4 * 8;
    short8 bfr[4];
#pragma unroll
    for (int nt = 0; nt < 4; ++nt)
      bfr[nt] = *(const short8*)(X + (long)(nt * 16 + l15) * E_ + k0);
#pragma unroll
    for (int mt = 0; mt < 8; ++mt) {
      int p = (wave * 8 + mt) * 16 + l15;
      short8 af = *(const short8*)(W + (long)p * 256 + k0);
#pragma unroll
      for (int nt = 0; nt < 4; ++nt)
        acc[mt][nt] = __builtin_amdgcn_mfma_f32_16x16x32_bf16(af, bfr[nt], acc[mt][nt], 0, 0, 0);
    }
  }

#pragma unroll
  for (int mt = 0; mt < 8; ++mt) {
    int jc = (wave * 8 + mt) * 4 + l4;
    f32x4 b4 = *(const f32x4*)(bias_p + ch * 1024 + jc * 4);
#pragma unroll
    for (int nt = 0; nt < 4; ++nt) {
      int b = nt * 16 + l15;
      u16x4 v;
#pragma unroll
      for (int g = 0; g < 4; ++g) v[g] = f2bf(acc[mt][nt][g] + b4[g]);
      long off = (((long)(ch * 512 + t) * 256 + jc) * 64 + b) * 4;
      *(u16x4*)(xz + off) = v;
    }
  }
}

// ---------- v18 LSTM: v10 poison-ring + own-col LDS shortcut + hin double-buffer ----------
// 32 blocks = (ch 2) x (bs 4) x (role 4), 512 threads. Store/poison path = v10 verbatim
// (hout + block-synchronized coalesced burst). Changes (traffic-reducers from v12, WITHOUT
// its direct-store regression):
//  * own 64 cols written to next step's hin during gates (LDS only; never cross the MALL)
//  * spin covers only 192 remote cols with 384 threads (-25% probe traffic)
//  * hin double-buffered so the own-col gate writes target the opposite buffer from
//    in-flight MFMA reads (race-free with the same 2 barriers/step)
__global__ __launch_bounds__(512) void lstm18(
    const short* __restrict__ wh, const short* __restrict__ xz,
    short* __restrict__ hring, float* __restrict__ out)
{
  const int bid  = blockIdx.x;
  const int ch   = bid >> 4;
  const int bs   = (bid >> 2) & 3;
  const int role = bid & 3;
  const int tid  = threadIdx.x;
  const int wave = tid >> 6, lane = tid & 63;
  const int l15 = lane & 15, l4 = lane >> 4;

  __shared__ short hin[2][16 * 256];   // 16 KB: double-buffered h_{t-1}, XOR-swizzled
  __shared__ short hout[16 * 64];      // 2 KB: this block's new h cols, XOR-swizzled

  for (int i = tid; i < 2 * 16 * 256; i += 512) ((short*)hin)[i] = 0;

  const short* whc = wh + (long)ch * 1024 * 256;

  // register-resident weight tiles: rows role*256 + wave*32 + mt*16 + l15
  short8 ah[2][8];
#pragma unroll
  for (int mt = 0; mt < 2; ++mt)
#pragma unroll
    for (int ks = 0; ks < 8; ++ks)
      ah[mt][ks] = *(const short8*)(whc + (long)(role * 256 + wave * 32 + mt * 16 + l15) * 256 + ks * 32 + l4 * 8);

  float cst[2], hmax[2];
#pragma unroll
  for (int mt = 0; mt < 2; ++mt) { cst[mt] = 0.f; hmax[mt] = -2.f; }

  short* rb = hring + ch * 16384;        // ch base (shorts)
  const int swzr = (l15 & 7) << 4;

  // poison/store coords (tid<256): own 64 cols, 16 rows x 16 chunks of 8B (v10 verbatim)
  const int sb = tid >> 4, sc = tid & 15;
  // spin/stage coords (tid<384): 16 rows x 24 remote 8-col chunks of 16B
  const int srow = tid / 24;             // 0..15
  const int schk = tid % 24;             // 0..23
  const int scol = (schk >= role * 8) ? (schk + 8) : schk;   // skip own 8 chunks
  const int active = tid < 384;

  __syncthreads();  // hin zero-init visible

  for (int t = 0; t < NSTEP; ++t) {
    int tok;
    if (ch == 0) tok = (t + 1) >> 1;
    else         tok = (t == NSTEP - 1) ? (S_ - 1) : ((t & 1) ? (t >> 1) : (t >> 1) + 1);

    // xz addends (normal cached loads; constant data)
    u16x4 xq[2];
#pragma unroll
    for (int mt = 0; mt < 2; ++mt) {
      int jc = role * 64 + wave * 8 + mt * 4 + l4;
      long off = (((long)(ch * 512 + tok) * 256 + jc) * 64 + (bs * 16 + l15)) * 4;
      xq[mt] = *(const u16x4*)(xz + off);
    }

    // ---- poison own rectangle in slot (t+1)&3 (drained by this thread's spin vmcnt) ----
    if (tid < 256) {
      short* pa = rb + ((t + 1) & 3) * 32768 + (bs * 16 + sb) * 256 + role * 64 + sc * 4;
      unsigned long long pv = 0xFFFFFFFFFFFFFFFFull;
      asm volatile("global_store_dwordx2 %0, %1, off sc1" :: "v"(pa), "v"(pv) : "memory");
    }

    // ---- spin+stage 192 remote cols of h_{t-1} from slot (t+3)&3: data IS the flag ----
    if (active) {
      const short* ga = rb + ((t + 3) & 3) * 32768 + (bs * 16 + srow) * 256 + scol * 8;
      short8 hv;
      int bad;
      do {
        asm volatile("global_load_dwordx4 %0, %1, off sc1\n\ts_waitcnt vmcnt(0)"
                     : "=v"(hv) : "v"(ga) : "memory");
        u32x4 dv = __builtin_bit_cast(u32x4, hv);
        bad = 0;
#pragma unroll
        for (int i = 0; i < 4; ++i) {
          unsigned d = dv[i];
          bad |= (d == 0xFFFFFFFFu);
        }
      } while (__ballot(bad));
      *(short8*)((char*)hin[t & 1] + srow * 512 + ((scol * 16) ^ ((srow & 7) << 4))) = hv;
    }
    __syncthreads();

    // ---- recurrent MFMAs: 2 M-tiles x 8 k-steps ----
    f32x4 acc[2];
    acc[0] = (f32x4){0.f, 0.f, 0.f, 0.f};
    acc[1] = (f32x4){0.f, 0.f, 0.f, 0.f};
    const char* hr = (const char*)hin[t & 1] + l15 * 512;
#pragma unroll
    for (int ks = 0; ks < 8; ++ks) {
      short8 hfr = *(const short8*)(hr + ((ks * 64 + l4 * 16) ^ swzr));
      acc[0] = __builtin_amdgcn_mfma_f32_16x16x32_bf16(ah[0][ks], hfr, acc[0], 0, 0, 0);
      acc[1] = __builtin_amdgcn_mfma_f32_16x16x32_bf16(ah[1][ks], hfr, acc[1], 0, 0, 0);
    }

    // ---- gates / state; own cols -> next hin buffer (LDS) + hout (v10 store path) ----
    char* hnext = (char*)hin[(t + 1) & 1] + l15 * 512;
#pragma unroll
    for (int mt = 0; mt < 2; ++mt) {
      float zi = acc[mt][0] + bf2f(xq[mt][0]);
      float zf = acc[mt][1] + bf2f(xq[mt][1]);
      float zg = acc[mt][2] + bf2f(xq[mt][2]);
      float zo = acc[mt][3] + bf2f(xq[mt][3]);
      float cc = cst[mt];
      cc = sigm(zf) * cc + sigm(zi) * tanh_(zg);
      float hh = sigm(zo) * tanh_(cc);
      cst[mt] = cc;
      hmax[mt] = fmaxf(hmax[mt], hh);
      unsigned short hb = f2bf(hh);
      int col = role * 64 + wave * 8 + mt * 4 + l4;
      int lc  = wave * 8 + mt * 4 + l4;   // local col 0..63
      *(short*)(hnext + ((col * 2) ^ swzr)) = (short)hb;  // own col, opposite buffer
      *(short*)((char*)hout + l15 * 128 + ((lc * 2) ^ ((l15 & 7) << 4))) = (short)hb;
    }
    __syncthreads();

    // ---- data store to slot t&3: block-synchronized burst (full-sector coalescing),
    //      NO drain, NO flag (visibility rides the next spin) -- v10 verbatim ----
    if (tid < 256) {
      unsigned long long val =
          *(const unsigned long long*)((const char*)hout + sb * 128 + ((sc * 8) ^ ((sb & 7) << 4)));
      short* ga = rb + (t & 3) * 32768 + (bs * 16 + sb) * 256 + role * 64 + sc * 4;
      asm volatile("global_store_dwordx2 %0, %1, off sc1" :: "v"(ga), "v"(val) : "memory");
    }
    // no trailing barrier: hout reuse is ordered by the next iteration's stage barrier;
    // hin buffers alternate so gate writes never collide with in-flight MFMA reads.
  }

  // ---- final: running maxes ----
#pragma unroll
  for (int mt = 0; mt < 2; ++mt) {
    int jc = role * 64 + wave * 8 + mt * 4 + l4;
    out[(long)(bs * 16 + l15) * (2 * H_) + ch * H_ + jc] = hmax[mt];
  }
}

extern "C" void kernel_launch(void* const* d_in, const int* in_sizes, int n_in,
                              void* d_out, int out_size, void* d_ws, size_t ws_size,
                              hipStream_t stream) {
  const float* x     = (const float*)d_in[0];
  const float* wih_f = (const float*)d_in[1];
  const float* whh_f = (const float*)d_in[2];
  const float* bih_f = (const float*)d_in[3];
  const float* bhh_f = (const float*)d_in[4];
  const float* wih_b = (const float*)d_in[5];
  const float* whh_b = (const float*)d_in[6];
  const float* bih_b = (const float*)d_in[7];
  const float* bhh_b = (const float*)d_in[8];

  char* ws = (char*)d_ws;
  short* x_bf   = (short*)(ws);                 // 16,777,216 B (dead after xz_gemm9)
  short* hring  = (short*)(ws);                 // 262,144 B ring (reuses x_bf region)
  short* wx     = (short*)(ws + 16777216);      //  1,048,576 B
  short* wh     = (short*)(ws + 17825792);      //  1,048,576 B
  float* bias_p = (float*)(ws + 18874368);      //      8,192 B
  short* xz     = (short*)(ws + 18882560);      // 134,217,728 B (bf16)

  const size_t NEED = 18882560UL + 134217728UL;   // 153,100,288
  if (ws_size < NEED) return;

  prep9<<<2048, 256, 0, stream>>>(x, wih_f, whh_f, bih_f, bhh_f,
                                  wih_b, whh_b, bih_b, bhh_b,
                                  x_bf, wx, wh, bias_p);
  xz_gemm9<<<1024, 512, 0, stream>>>(x_bf, wx, bias_p, xz);

  // x_bf dead; init ring: slots 0..2 = poison (0xFF bytes), slot 3 = zeros (h_{-1} = 0).
  hipMemsetAsync(ws, 0xFF, 196608, stream);
  hipMemsetAsync(ws + 196608, 0, 65536, stream);

  lstm18<<<32, 512, 0, stream>>>(wh, xz, hring, (float*)d_out);
}